// Round 1
// baseline (184.924 us; speedup 1.0000x reference)
//
#include <hip/hip_runtime.h>
#include <math.h>

#define NSEQ 32
#define NH   32
#define NKV  8
#define GRP  4
#define DIM  128
#define NSH  4
#define LSH  1024
#define ITERS 128            // LSH / 8 positions-per-iteration
#define KVSTRIDE (NKV*DIM)   // floats between consecutive kv positions = 1024

#define MOFF ((size_t)NSH*NSEQ*NKV*GRP*DIM)            // 524288 floats
#define SOFF (MOFF + (size_t)NSH*NSEQ*NKV*GRP)         // +4096

// ---------------- Kernel 1: per-(shard, seq, kv-head) partial attention ----
__global__ __launch_bounds__(256, 4) void attn_partial_kernel(
    const float* __restrict__ q, const float* __restrict__ kk,
    const float* __restrict__ vv, float* __restrict__ ws) {
  const int kvh = blockIdx.x;   // 0..7
  const int n   = blockIdx.y;   // 0..31
  const int sh  = blockIdx.z;   // 0..3
  const int tid = threadIdx.x;  // 0..255
  const int w    = tid >> 6;          // wave 0..3
  const int lane = tid & 63;
  const int sub  = lane & 31;         // d-slice index (sub*4 .. sub*4+3)
  const int pgrp = (w << 1) | (lane >> 5);  // position group 0..7

  // q fragments for the 4 GQA heads sharing this kv head, pre-scaled
  const float scale = 0.08838834764831845f; // 128^-0.5
  const float* qp = q + ((size_t)n * NH + (size_t)kvh * GRP) * DIM + sub * 4;
  float4 qv0 = *(const float4*)(qp + 0 * DIM);
  float4 qv1 = *(const float4*)(qp + 1 * DIM);
  float4 qv2 = *(const float4*)(qp + 2 * DIM);
  float4 qv3 = *(const float4*)(qp + 3 * DIM);
#define SCQ(Q) Q.x *= scale; Q.y *= scale; Q.z *= scale; Q.w *= scale
  SCQ(qv0); SCQ(qv1); SCQ(qv2); SCQ(qv3);
#undef SCQ

  // online-softmax state, per lane: 4 heads x (m, sum, acc[4 d-elems])
  float m0 = -1e30f, m1 = -1e30f, m2 = -1e30f, m3 = -1e30f;
  float s0 = 0.f, s1 = 0.f, s2 = 0.f, s3 = 0.f;
  float4 a0 = make_float4(0.f,0.f,0.f,0.f);
  float4 a1 = a0, a2 = a0, a3 = a0;

  const size_t blkoff = ((size_t)sh * NSEQ + n) * LSH * (size_t)KVSTRIDE
                        + (size_t)kvh * DIM + sub * 4;
  const float* kb = kk + blkoff;
  const float* vb = vv + blkoff;

  auto process = [&](const float4 kc, const float4 vc) {
    float d0 = kc.x*qv0.x + kc.y*qv0.y + kc.z*qv0.z + kc.w*qv0.w;
    float d1 = kc.x*qv1.x + kc.y*qv1.y + kc.z*qv1.z + kc.w*qv1.w;
    float d2 = kc.x*qv2.x + kc.y*qv2.y + kc.z*qv2.z + kc.w*qv2.w;
    float d3 = kc.x*qv3.x + kc.y*qv3.y + kc.z*qv3.z + kc.w*qv3.w;
#pragma unroll
    for (int off = 1; off < 32; off <<= 1) {
      d0 += __shfl_xor(d0, off, 32);
      d1 += __shfl_xor(d1, off, 32);
      d2 += __shfl_xor(d2, off, 32);
      d3 += __shfl_xor(d3, off, 32);
    }
    // rare rescale path: new running max found
    if (d0 > m0 || d1 > m1 || d2 > m2 || d3 > m3) {
      float nm0 = fmaxf(m0, d0), nm1 = fmaxf(m1, d1);
      float nm2 = fmaxf(m2, d2), nm3 = fmaxf(m3, d3);
      float r0 = __expf(m0 - nm0), r1 = __expf(m1 - nm1);
      float r2 = __expf(m2 - nm2), r3 = __expf(m3 - nm3);
      s0 *= r0; s1 *= r1; s2 *= r2; s3 *= r3;
      a0.x *= r0; a0.y *= r0; a0.z *= r0; a0.w *= r0;
      a1.x *= r1; a1.y *= r1; a1.z *= r1; a1.w *= r1;
      a2.x *= r2; a2.y *= r2; a2.z *= r2; a2.w *= r2;
      a3.x *= r3; a3.y *= r3; a3.z *= r3; a3.w *= r3;
      m0 = nm0; m1 = nm1; m2 = nm2; m3 = nm3;
    }
    float p0 = __expf(d0 - m0), p1 = __expf(d1 - m1);
    float p2 = __expf(d2 - m2), p3 = __expf(d3 - m3);
    s0 += p0; s1 += p1; s2 += p2; s3 += p3;
    a0.x = fmaf(p0, vc.x, a0.x); a0.y = fmaf(p0, vc.y, a0.y);
    a0.z = fmaf(p0, vc.z, a0.z); a0.w = fmaf(p0, vc.w, a0.w);
    a1.x = fmaf(p1, vc.x, a1.x); a1.y = fmaf(p1, vc.y, a1.y);
    a1.z = fmaf(p1, vc.z, a1.z); a1.w = fmaf(p1, vc.w, a1.w);
    a2.x = fmaf(p2, vc.x, a2.x); a2.y = fmaf(p2, vc.y, a2.y);
    a2.z = fmaf(p2, vc.z, a2.z); a2.w = fmaf(p2, vc.w, a2.w);
    a3.x = fmaf(p3, vc.x, a3.x); a3.y = fmaf(p3, vc.y, a3.y);
    a3.z = fmaf(p3, vc.z, a3.z); a3.w = fmaf(p3, vc.w, a3.w);
  };

  // depth-2 software pipeline (prefetch 2 iterations = 16 positions ahead)
  float4 k0 = *(const float4*)(kb + (size_t)(0 * 8 + pgrp) * KVSTRIDE);
  float4 v0 = *(const float4*)(vb + (size_t)(0 * 8 + pgrp) * KVSTRIDE);
  float4 k1 = *(const float4*)(kb + (size_t)(1 * 8 + pgrp) * KVSTRIDE);
  float4 v1 = *(const float4*)(vb + (size_t)(1 * 8 + pgrp) * KVSTRIDE);

  for (int it = 0; it < ITERS; it += 2) {
    const int p2i = (it + 2) & (ITERS - 1);   // wraps on last iter (harmless)
    const int p3i = (it + 3) & (ITERS - 1);
    float4 nk0 = *(const float4*)(kb + (size_t)(p2i * 8 + pgrp) * KVSTRIDE);
    float4 nv0 = *(const float4*)(vb + (size_t)(p2i * 8 + pgrp) * KVSTRIDE);
    float4 nk1 = *(const float4*)(kb + (size_t)(p3i * 8 + pgrp) * KVSTRIDE);
    float4 nv1 = *(const float4*)(vb + (size_t)(p3i * 8 + pgrp) * KVSTRIDE);
    process(k0, v0);
    process(k1, v1);
    k0 = nk0; v0 = nv0; k1 = nk1; v1 = nv1;
  }

  // ---- merge the two 32-lane halves of each wave (shuffle across lane^32) --
#define HALF_MERGE(mX, sX, aX) do {                       \
    float om_ = __shfl_xor(mX, 32, 64);                   \
    float nm_ = fmaxf(mX, om_);                           \
    float ea_ = __expf(mX - nm_), eb_ = __expf(om_ - nm_);\
    float os_ = __shfl_xor(sX, 32, 64);                   \
    sX = sX * ea_ + os_ * eb_;                            \
    float t_;                                             \
    t_ = __shfl_xor(aX.x, 32, 64); aX.x = aX.x*ea_ + t_*eb_; \
    t_ = __shfl_xor(aX.y, 32, 64); aX.y = aX.y*ea_ + t_*eb_; \
    t_ = __shfl_xor(aX.z, 32, 64); aX.z = aX.z*ea_ + t_*eb_; \
    t_ = __shfl_xor(aX.w, 32, 64); aX.w = aX.w*ea_ + t_*eb_; \
    mX = nm_;                                             \
  } while (0)
  HALF_MERGE(m0, s0, a0);
  HALF_MERGE(m1, s1, a1);
  HALF_MERGE(m2, s2, a2);
  HALF_MERGE(m3, s3, a3);
#undef HALF_MERGE

  // ---- merge across the 4 waves through LDS -------------------------------
  __shared__ float lm[4][GRP][32];
  __shared__ float lsum[4][GRP][32];
  __shared__ float la[4][GRP][32][4];
  if ((lane >> 5) == 0) {
#define STORE_G(gi, mX, sX, aX)                                   \
    lm[w][gi][sub] = mX; lsum[w][gi][sub] = sX;                   \
    la[w][gi][sub][0] = aX.x; la[w][gi][sub][1] = aX.y;           \
    la[w][gi][sub][2] = aX.z; la[w][gi][sub][3] = aX.w;
    STORE_G(0, m0, s0, a0)
    STORE_G(1, m1, s1, a1)
    STORE_G(2, m2, s2, a2)
    STORE_G(3, m3, s3, a3)
#undef STORE_G
  }
  __syncthreads();

  if (tid < 128) {
    const int gi = tid >> 5;
    const int sb = tid & 31;
    float M = -1e30f, SS = 0.f;
    float A0 = 0.f, A1 = 0.f, A2 = 0.f, A3 = 0.f;
#pragma unroll
    for (int wv = 0; wv < 4; ++wv) {
      float mm = lm[wv][gi][sb];
      float nm = fmaxf(M, mm);
      float ra = __expf(M - nm), rb = __expf(mm - nm);
      SS = SS * ra + lsum[wv][gi][sb] * rb;
      A0 = A0 * ra + la[wv][gi][sb][0] * rb;
      A1 = A1 * ra + la[wv][gi][sb][1] * rb;
      A2 = A2 * ra + la[wv][gi][sb][2] * rb;
      A3 = A3 * ra + la[wv][gi][sb][3] * rb;
      M = nm;
    }
    const size_t idx = (((size_t)sh * NSEQ + n) * NKV + kvh) * GRP + gi;
    *(float4*)(ws + idx * DIM + sb * 4) = make_float4(A0, A1, A2, A3);
    ws[MOFF + idx] = M;
    ws[SOFF + idx] = SS;
  }
}

// ---------------- Kernel 2: online-softmax merge across the 4 shards -------
__global__ __launch_bounds__(128) void attn_merge_kernel(
    const float* __restrict__ ws, float* __restrict__ out) {
  const int kvh = blockIdx.x;
  const int n   = blockIdx.y;
  const int d   = threadIdx.x;  // 0..127
#pragma unroll
  for (int gi = 0; gi < GRP; ++gi) {
    size_t idx[NSH];
    float mm[NSH];
    float M = -1e30f;
#pragma unroll
    for (int s2 = 0; s2 < NSH; ++s2) {
      idx[s2] = (((size_t)s2 * NSEQ + n) * NKV + kvh) * GRP + gi;
      mm[s2] = ws[MOFF + idx[s2]];
      M = fmaxf(M, mm[s2]);
    }
    float num = 0.f, den = 0.f;
#pragma unroll
    for (int s2 = 0; s2 < NSH; ++s2) {
      float wg = __expf(mm[s2] - M);
      den += wg * ws[SOFF + idx[s2]];
      num += wg * ws[idx[s2] * DIM + d];
    }
    out[((size_t)n * NH + (size_t)kvh * GRP + gi) * DIM + d] = num / den;
  }
}

extern "C" void kernel_launch(void* const* d_in, const int* in_sizes, int n_in,
                              void* d_out, int out_size, void* d_ws, size_t ws_size,
                              hipStream_t stream) {
  const float* q = (const float*)d_in[0];
  const float* k = (const float*)d_in[1];
  const float* v = (const float*)d_in[2];
  float* out = (float*)d_out;
  float* ws  = (float*)d_ws;

  attn_partial_kernel<<<dim3(NKV, NSEQ, NSH), 256, 0, stream>>>(q, k, v, ws);
  attn_merge_kernel<<<dim3(NKV, NSEQ), 128, 0, stream>>>(ws, out);
}